// Round 10
// baseline (35.778 us; speedup 1.0000x reference)
//
#include <hip/hip_runtime.h>
#include <stdint.h>

// PropNet cost-volume via bf16 MFMA.
// Prep: streaming transpose of BOTH x and y to bf16 [n][cq][pix][8ch]
//   (1KB-contiguous reads AND writes; per-pixel norm partials in-thread).
// Main: whole-tile single-burst global_load_lds staging (8 sub-buffers),
//   per-chunk counted-vmcnt gates + raw s_barrier — vmcnt(0) only at
//   phase ends, never per chunk. No pack phase, no re-issue.
// N=2, C=256, H=W=96, max_distance=4 (window 9x9), num_class=124.
#define Nn 2
#define Cc 256
#define Hh 96
#define Ww 96
#define HW (Hh * Ww)
#define MD 4
#define NC 124
#define TH 4                    // dest tile rows
#define TWD 8                   // dest tile cols
#define NQ (TH * TWD)           // 32 dest pixels (MFMA M)
#define SH (TH + 2 * MD)        // 12 window rows
#define SWD (TWD + 2 * MD)      // 16 window cols
#define NS (SH * SWD)           // 192 src pixels (MFMA N)
#define BLK 256                 // 4 waves
#define NBW (Ww / TWD)          // 12
#define NBH (Hh / TH)           // 24
#define NBLK (Nn * NBH * NBW)   // 576 blocks (divisible by 8)
#define YROW 64                 // bytes per pixel row in a chunk (32 ch * 2B)
#define XOFF (NS * YROW)        // 12288: x region offset inside a sub-buffer
#define BUFSZ (XOFF + NQ * YROW) // 14336 bytes per 32-ch sub-buffer
#define NST 4                   // sub-buffers resident per phase (57344 B)
#define TBL (NQ * NC)           // 3968 table entries (15872B <= NST*BUFSZ)
#define CQ 32                   // 8-channel groups in C=256

// prep geometry: block = 256 px x 64 ch x one tensor
#define PPX 256
#define NSTR (HW / PPX)         // 36 strips
#define PBLK (2 * Nn * 4 * NSTR)  // 576 blocks

// workspace layout (bytes)
#define TEN_BYTES ((size_t)Nn * CQ * HW * 16)   // 9.44 MB per tensor
#define XT_OFF    TEN_BYTES
#define PART_OFF  (TEN_BYTES * 2)               // parts[ten][g4][n][HW] f32

typedef short short8 __attribute__((ext_vector_type(8)));
typedef float f32x4 __attribute__((ext_vector_type(4)));

// Monotone float -> uint mapping so unsigned min == float min.
__device__ __forceinline__ unsigned fmap(float f) {
    unsigned b = __float_as_uint(f);
    return (b & 0x80000000u) ? ~b : (b | 0x80000000u);
}
__device__ __forceinline__ float funmap(unsigned u) {
    unsigned b = (u & 0x80000000u) ? (u & 0x7fffffffu) : ~u;
    return __uint_as_float(b);
}
// XOR-swizzled byte offset of 16B ch-slot `slot` in pixel-row `row`.
__device__ __forceinline__ int swz(int row, int slot) {
    return row * YROW + ((slot ^ ((row >> 1) & 3)) << 4);
}

// ---------------- prep: fp32 NCHW -> bf16 [n][cq][pix][8], norm partials ----
__global__ __launch_bounds__(256) void prep_t(
    const float* __restrict__ x, const float* __restrict__ y,
    uint4* __restrict__ yT, uint4* __restrict__ xT, float* __restrict__ parts)
{
    __shared__ float tile[64 * PPX];   // 64 KB fp32 staging [chL][px]
    const int t = threadIdx.x;
    const int bid = blockIdx.x;
    const int strip = bid % NSTR;
    const int rest  = bid / NSTR;      // 0..15
    const int g4  = rest & 3;          // channel quarter (64 ch)
    const int n   = (rest >> 2) & 1;
    const int ten = rest >> 3;         // 0 = y, 1 = x
    const int pix0 = strip * PPX;
    const float* src = (ten ? x : y) + ((size_t)n * Cc + g4 * 64) * HW + pix0;
    uint4* dstT = (ten ? xT : yT) + (size_t)n * CQ * HW;

    const int wid = t >> 6, lane = t & 63;
    // 16 loads/thread; each wave-inst = one channel row-segment = 1KB contiguous.
#pragma unroll
    for (int k = 0; k < 16; ++k) {
        const int m = wid * 16 + k;    // local channel 0..63
        const float4 v = *(const float4*)(src + (size_t)m * HW + lane * 4);
        *(float4*)&tile[m * PPX + lane * 4] = v;
    }
    __syncthreads();

    // pack: thread owns px = t for all 8 local cq slices -> norms in-thread.
    float sq = 0.f;
#pragma unroll
    for (int k = 0; k < 8; ++k) {
        float v[8];
#pragma unroll
        for (int j = 0; j < 8; ++j) v[j] = tile[(k * 8 + j) * PPX + t];
        unsigned pk[4];
#pragma unroll
        for (int j = 0; j < 4; ++j) {
            sq = fmaf(v[2*j],   v[2*j],   sq);
            sq = fmaf(v[2*j+1], v[2*j+1], sq);
            pk[j] = (__float_as_uint(v[2*j]) >> 16) |
                    (__float_as_uint(v[2*j+1]) & 0xffff0000u);
        }
        dstT[(size_t)(g4 * 8 + k) * HW + pix0 + t] =
            make_uint4(pk[0], pk[1], pk[2], pk[3]);   // 1KB contiguous runs
    }
    parts[((size_t)(ten * 4 + g4) * Nn + n) * HW + pix0 + t] = sq;
}

// ---------------- main kernel ---------------------------------------------
__global__ __launch_bounds__(BLK, 2) void propnet_mfma(
    const uint4* __restrict__ yT, const uint4* __restrict__ xT,
    const float* __restrict__ parts, const int* __restrict__ labels,
    float* __restrict__ out)
{
    __shared__ __align__(16) unsigned char S[NST * BUFSZ];  // 57344 B staging
    __shared__ float y2s[NS];
    __shared__ float x2s[NQ];
    __shared__ int   labs[NS];
    unsigned* table = (unsigned*)S;   // aliased after the K-loop

    const int t = threadIdx.x;

    // XCD-aware bijective swizzle: contiguous 72-block chunk per XCD.
    const int orig = blockIdx.x;
    const int lin  = (orig & 7) * (NBLK / 8) + (orig >> 3);
    const int n    = lin / (NBH * NBW);
    const int rem  = lin - n * (NBH * NBW);
    const int h0   = (rem / NBW) * TH;
    const int w0   = (rem % NBW) * TWD;

    const float* ypart = parts;                       // [4][Nn][HW]
    const float* xpart = parts + (size_t)4 * Nn * HW;

    if (t < NS) {
        const int sr = t >> 4, sc = t & 15;
        const int gh = h0 - MD + sr, gw = w0 - MD + sc;
        const bool ok = (gh >= 0) && (gh < Hh) && (gw >= 0) && (gw < Ww);
        labs[t] = ok ? labels[(size_t)n * HW + gh * Ww + gw] : -1;  // -1: excluded
        float s = 0.f;
        if (ok) {
            const size_t idx = (size_t)n * HW + gh * Ww + gw;
#pragma unroll
            for (int g = 0; g < 4; ++g) s += ypart[(size_t)g * Nn * HW + idx];
        }
        y2s[t] = s;
    }
    if (t < NQ) {
        const size_t idx = (size_t)n * HW + (size_t)(h0 + (t >> 3)) * Ww + (w0 + (t & 7));
        float s = 0.f;
#pragma unroll
        for (int g = 0; g < 4; ++g) s += xpart[(size_t)g * Nn * HW + idx];
        x2s[t] = s;
    }
    // Drain prologue VMEM so the gate counts below are exact.
    asm volatile("s_waitcnt vmcnt(0)" ::: "memory");

    const int lane = t & 63;
    const int wid  = t >> 6;

    // ---- y DMA descriptors: 3 insts/wave/chunk; linear LDS dest, swizzle
    // realized by permuting the per-lane GLOBAL source (rule #21).
    size_t ysrc[3]; int yl[3];
    {
        const int sc4 = lane >> 2;                 // pixel col within 16-group
        const int pos = lane & 3;                  // 16B position in pixel row
        const int cqw = pos ^ ((sc4 >> 1) & 3);    // ch-slot stored at this pos
#pragma unroll
        for (int i = 0; i < 3; ++i) {
            const int g  = wid * 3 + i;            // window row 0..11
            const int gh = min(max(h0 - MD + g, 0), Hh - 1);   // clamp; excluded by labs
            const int gw = min(max(w0 - MD + sc4, 0), Ww - 1);
            ysrc[i] = (size_t)cqw * HW + (size_t)gh * Ww + gw;
            yl[i]   = g * 1024;                    // 16 pixels * 64B
        }
    }
    // ---- x DMA descriptors: 2 insts/wave/phase; this wave stages the x of
    // chunk-local cl == wid (halves j = 0,1).
    size_t xsrc[2]; int xl[2];
#pragma unroll
    for (int j = 0; j < 2; ++j) {
        const int q   = j * 16 + (lane >> 2);      // dest pixel 0..31
        const int pos = lane & 3;
        const int s   = pos ^ ((q >> 1) & 3);      // slot stored at this pos
        xsrc[j] = (size_t)s * HW + (size_t)(h0 + (q >> 3)) * Ww + (w0 + (q & 7));
        xl[j]   = wid * BUFSZ + XOFF + j * 1024;
    }
    const uint4* yTn = yT + (size_t)n * CQ * HW;
    const uint4* xTn = xT + (size_t)n * CQ * HW;

    // Issue order per wave per phase (14 insts, uniform): x j=0,1 then
    // chunk-major y (3 per chunk-local). Gate for chunk-local cl:
    // vmcnt(9-3*cl)  ==  own x + y of chunks <= cl retired; s_barrier joins.
    auto stage_phase = [&](int p) {
        const size_t xc = (size_t)((p * 4 + wid) * 4) * HW;
#pragma unroll
        for (int j = 0; j < 2; ++j)
            __builtin_amdgcn_global_load_lds(
                (const __attribute__((address_space(1))) unsigned int*)(xTn + xc + xsrc[j]),
                (__attribute__((address_space(3))) unsigned int*)(S + xl[j]),
                16, 0, 0);
#pragma unroll
        for (int cl = 0; cl < 4; ++cl) {
            const size_t yc = (size_t)((p * 4 + cl) * 4) * HW;
#pragma unroll
            for (int i = 0; i < 3; ++i)
                __builtin_amdgcn_global_load_lds(
                    (const __attribute__((address_space(1))) unsigned int*)(yTn + yc + ysrc[i]),
                    (__attribute__((address_space(3))) unsigned int*)(S + cl * BUFSZ + yl[i]),
                    16, 0, 0);
        }
    };

    // ---- MFMA fragments ----
    const int l15 = lane & 15;
    const int lg  = lane >> 4;        // 8-ch k-slot
    int aoff[2], boff[3];
#pragma unroll
    for (int mf = 0; mf < 2; ++mf) aoff[mf] = XOFF + swz(mf * 16 + l15, lg);
#pragma unroll
    for (int nf = 0; nf < 3; ++nf) boff[nf] = swz(wid * 48 + nf * 16 + l15, lg);

    f32x4 acc[2][3];
#pragma unroll
    for (int mf = 0; mf < 2; ++mf)
#pragma unroll
        for (int nf = 0; nf < 3; ++nf)
            acc[mf][nf] = (f32x4){0.f, 0.f, 0.f, 0.f};

    auto compute = [&](const unsigned char* bb) {
        short8 a[2], b[3];
#pragma unroll
        for (int mf = 0; mf < 2; ++mf) a[mf] = *(const short8*)(bb + aoff[mf]);
#pragma unroll
        for (int nf = 0; nf < 3; ++nf) b[nf] = *(const short8*)(bb + boff[nf]);
#pragma unroll
        for (int mf = 0; mf < 2; ++mf)
#pragma unroll
            for (int nf = 0; nf < 3; ++nf)
                acc[mf][nf] = __builtin_amdgcn_mfma_f32_16x16x32_bf16(
                    a[mf], b[nf], acc[mf][nf], 0, 0, 0);
    };

#define GATE(N)                                                      \
    asm volatile("s_waitcnt vmcnt(" #N ")" ::: "memory");            \
    __builtin_amdgcn_sched_barrier(0);                               \
    __builtin_amdgcn_s_barrier();                                    \
    __builtin_amdgcn_sched_barrier(0);

    // ---- K-loop: two phases of 4 chunks; one burst + counted gates each.
    stage_phase(0);
    GATE(9); compute(S);
    GATE(6); compute(S + BUFSZ);
    GATE(3); compute(S + 2 * BUFSZ);
    GATE(0); compute(S + 3 * BUFSZ);
    // Phase boundary: every wave's LDS reads must complete before phase-2
    // DMA overwrites the regions (rule 18: lgkm + sched fences + barrier).
    asm volatile("s_waitcnt lgkmcnt(0)" ::: "memory");
    __builtin_amdgcn_sched_barrier(0);
    __builtin_amdgcn_s_barrier();
    __builtin_amdgcn_sched_barrier(0);
    stage_phase(1);
    GATE(9); compute(S);
    GATE(6); compute(S + BUFSZ);
    GATE(3); compute(S + 2 * BUFSZ);
    GATE(0); compute(S + 3 * BUFSZ);
#undef GATE

    __syncthreads();   // join before aliasing the staging region as table

    // ---- init tables (staging dead now) ----
    for (int i = t; i < TBL; i += BLK) table[i] = 0xBF800000u;  // fmap(1.0f)
    __syncthreads();

    // ---- epilogue: d -> sigmoid -> label-masked min ----
    // C layout: col(n) = l&15, row(m) = (l>>4)*4 + reg.
#pragma unroll
    for (int mf = 0; mf < 2; ++mf) {
#pragma unroll
        for (int nf = 0; nf < 3; ++nf) {
#pragma unroll
            for (int r = 0; r < 4; ++r) {
                const int q = mf * 16 + lg * 4 + r;       // dest pixel 0..31
                const int s = wid * 48 + nf * 16 + l15;   // src pixel 0..191
                const int qr = q >> 3, qc = q & 7;
                const int sr = s >> 4, sc = s & 15;
                const int di = sr - qr, dj = sc - qc;
                const int lab = labs[s];
                if (di >= 0 && di <= 2 * MD && dj >= 0 && dj <= 2 * MD &&
                    lab >= 0 && lab < NC) {
                    const float d  = x2s[q] + y2s[s] - 2.0f * acc[mf][nf][r];
                    const float sg = 1.0f / (1.0f + __expf(-d));
                    atomicMin(&table[q * NC + lab], fmap(fmaf(2.0f, sg, -1.0f)));
                }
            }
        }
    }
    __syncthreads();

    // ---- write out[n][class][h0+qr][w0+qc] ----
    const size_t ob = (size_t)n * NC * HW;
    for (int i = t; i < TBL; i += BLK) {
        const int g = i >> 5;        // class
        const int q = i & 31;        // dest pixel
        const int qr = q >> 3, qc = q & 7;
        out[ob + (size_t)g * HW + (size_t)(h0 + qr) * Ww + (w0 + qc)] =
            funmap(table[q * NC + g]);
    }
}

extern "C" void kernel_launch(void* const* d_in, const int* in_sizes, int n_in,
                              void* d_out, int out_size, void* d_ws, size_t ws_size,
                              hipStream_t stream) {
    const float* x      = (const float*)d_in[0];
    const float* y      = (const float*)d_in[1];
    const int*   labels = (const int*)d_in[2];
    float*       out    = (float*)d_out;
    uint4* yT    = (uint4*)d_ws;
    uint4* xT    = (uint4*)((char*)d_ws + XT_OFF);
    float* parts = (float*)((char*)d_ws + PART_OFF);
    (void)in_sizes; (void)n_in; (void)out_size; (void)ws_size;

    prep_t<<<dim3(PBLK), dim3(256), 0, stream>>>(x, y, yT, xT, parts);
    propnet_mfma<<<dim3(NBLK), dim3(BLK), 0, stream>>>(yT, xT, parts, labels, out);
}

// Round 11
// 32.419 us; speedup vs baseline: 1.1036x; 1.1036x over previous
//
#include <hip/hip_runtime.h>
#include <stdint.h>

// PropNet cost-volume via bf16 MFMA — single fused kernel, 8x8 dest tile
// (288 blocks, window 16x16=256, overlap 4x vs 6x), 8 waves. r6 skeleton:
// DMA fp32 window -> LDS F, pack to swizzled bf16 B, MFMA, fused epilogue.
// Plain __syncthreads (counted-vmcnt gates measured slower on this kernel).
// N=2, C=256, H=W=96, max_distance=4 (window 9x9), num_class=124.
#define Nn 2
#define Cc 256
#define Hh 96
#define Ww 96
#define HW (Hh * Ww)
#define MD 4
#define NC 124
#define TH 8                    // dest tile rows
#define TWD 8                   // dest tile cols
#define NQ (TH * TWD)           // 64 dest pixels (MFMA M)
#define SH (TH + 2 * MD)        // 16 window rows
#define SWD (TWD + 2 * MD)      // 16 window cols
#define NS (SH * SWD)           // 256 src pixels (MFMA N)
#define BLK 512                 // 8 waves
#define NBW (Ww / TWD)          // 12
#define NBH (Hh / TH)           // 12
#define NBLK (Nn * NBH * NBW)   // 288 blocks (divisible by 8)
#define YROW 64                 // bytes per pixel row in a chunk (32 ch * 2B)
#define XB (NS * YROW)          // 16384: x region offset inside B
#define BUFSZ (XB + NQ * YROW)  // 20480 bytes
#define FYW (32 * NS)           // 8192 words fp32 y staging
#define FXW (32 * NQ)           // 2048 words fp32 x staging
#define TBL (NQ * NC)           // 7936 table entries (31744B <= FYW*4)

typedef short short8 __attribute__((ext_vector_type(8)));
typedef float f32x4 __attribute__((ext_vector_type(4)));

// Monotone float -> uint mapping so unsigned min == float min.
__device__ __forceinline__ unsigned fmap(float f) {
    unsigned b = __float_as_uint(f);
    return (b & 0x80000000u) ? ~b : (b | 0x80000000u);
}
__device__ __forceinline__ float funmap(unsigned u) {
    unsigned b = (u & 0x80000000u) ? (u & 0x7fffffffu) : ~u;
    return __uint_as_float(b);
}
// XOR-swizzled byte offset of 16B ch-slot `slot` in pixel-row `row`.
// Used by BOTH the pack writes and the fragment reads -> always consistent.
__device__ __forceinline__ int swz(int row, int slot) {
    return row * YROW + ((slot ^ ((row >> 1) & 3)) << 4);
}

__global__ __launch_bounds__(BLK, 4) void propnet_fused(
    const float* __restrict__ x, const float* __restrict__ y,
    const int* __restrict__ labels, float* __restrict__ out)
{
    __shared__ __align__(16) float F[FYW + FXW];          // 40 KB fp32 staging
    __shared__ __align__(16) unsigned char B[BUFSZ];      // 20 KB bf16 operands
    __shared__ float y2s[NS];
    __shared__ float x2s[NQ];
    __shared__ int   labs[NS];
    unsigned* table = (unsigned*)F;   // aliased after the K-loop

    const int t = threadIdx.x;

    // XCD-aware bijective swizzle: contiguous 36-block chunk per XCD.
    const int orig = blockIdx.x;
    const int lin  = (orig & 7) * (NBLK / 8) + (orig >> 3);
    const int n    = lin / (NBH * NBW);
    const int rem  = lin - n * (NBH * NBW);
    const int h0   = (rem / NBW) * TH;
    const int w0   = (rem % NBW) * TWD;
    const size_t nb = (size_t)n * Cc * HW;

    if (t < NS) {
        const int sr = t >> 4, sc = t & 15;
        const int gh = h0 - MD + sr, gw = w0 - MD + sc;
        const bool ok = (gh >= 0) && (gh < Hh) && (gw >= 0) && (gw < Ww);
        labs[t] = ok ? labels[(size_t)n * HW + gh * Ww + gw] : -1;  // -1: excluded
        y2s[t]  = 0.f;
    }
    if (t < NQ) x2s[t] = 0.f;

    const int lane = t & 63;
    const int wid  = t >> 6;          // 0..7

    // ---- y DMA: 32 insts/chunk (4/wave); inst stages channel ch = wid*4+k,
    // lane = window segment (g = lane>>2 row, seg = lane&3). F[ch][px] linear
    // (px = g*16 + seg*4 + i). Edge rows/segs clamp in-range (excluded via labs).
    int yghw;                          // per-lane (gh*Ww + ws), ch-independent
    {
        const int g  = lane >> 2;
        const int sg = lane & 3;
        const int gh = min(max(h0 - MD + g, 0), Hh - 1);
        const int ws = min(max(w0 - MD + sg * 4, 0), Ww - 4);
        yghw = gh * Ww + ws;
    }
    // ---- x DMA: 8 insts/chunk (1/wave); inst covers ch wid*4..+3 (16 lanes
    // each), lane&15 = 4-px group of the 8x8 dest tile. Xf[ch][q] linear.
    int xsoff;                         // per-lane (ch<<? ) local offset
    {
        const int chl = lane >> 4;             // 0..3 within the wave's 4 ch
        const int qg  = lane & 15;             // 4-px group, q0 = qg*4
        const int qr  = qg >> 1, qc0 = (qg & 1) * 4;
        xsoff = chl * HW + (h0 + qr) * Ww + (w0 + qc0);
    }
    const float* ybp = y + nb;
    const float* xbp = x + nb;
    auto stage = [&](int c) {
        const size_t coff = (size_t)(c * 32) * HW;
#pragma unroll
        for (int k = 0; k < 4; ++k) {
            const int ch = wid * 4 + k;
            __builtin_amdgcn_global_load_lds(
                (const __attribute__((address_space(1))) unsigned int*)
                    (ybp + coff + (size_t)ch * HW + yghw),
                (__attribute__((address_space(3))) unsigned int*)
                    ((char*)F + ch * (NS * 4)),
                16, 0, 0);
        }
        __builtin_amdgcn_global_load_lds(
            (const __attribute__((address_space(1))) unsigned int*)
                (xbp + coff + (size_t)(wid * 4) * HW + xsoff),
            (__attribute__((address_space(3))) unsigned int*)
                ((char*)F + FYW * 4 + wid * 1024),
            16, 0, 0);
    };

    // ---- pack: y 1024 tasks (2/thread) + x 256 tasks (t<256). ----
    int ypx[2], ywb[2], yco[2];
#pragma unroll
    for (int i = 0; i < 2; ++i) {
        const int task = t + BLK * i;
        const int px   = task & 255;
        const int slot = task >> 8;
        ypx[i] = px;
        ywb[i] = swz(px, slot);
        yco[i] = slot * 8 * NS + px;      // F word offset, stride NS per ch
    }
    const bool xw = (t < 256);
    int xpx = 0, xwb = 0, xco = 0;
    if (xw) {
        xpx = t & 63;
        const int slot = t >> 6;
        xwb = XB + swz(xpx, slot);
        xco = FYW + slot * 8 * NQ + xpx;  // F word offset, stride NQ per ch
    }
    float ysq[2] = {0.f, 0.f};
    float xsq = 0.f;
    auto pack = [&]() {
#pragma unroll
        for (int i = 0; i < 2; ++i) {
            float v[8];
#pragma unroll
            for (int j = 0; j < 8; ++j) v[j] = F[yco[i] + j * NS];
            unsigned pk[4];
#pragma unroll
            for (int j = 0; j < 4; ++j) {
                ysq[i] = fmaf(v[2*j],   v[2*j],   ysq[i]);
                ysq[i] = fmaf(v[2*j+1], v[2*j+1], ysq[i]);
                pk[j] = (__float_as_uint(v[2*j]) >> 16) |
                        (__float_as_uint(v[2*j+1]) & 0xffff0000u);
            }
            *(uint4*)(B + ywb[i]) = make_uint4(pk[0], pk[1], pk[2], pk[3]);
        }
        if (xw) {
            float v[8];
#pragma unroll
            for (int j = 0; j < 8; ++j) v[j] = F[xco + j * NQ];
            unsigned pk[4];
#pragma unroll
            for (int j = 0; j < 4; ++j) {
                xsq = fmaf(v[2*j],   v[2*j],   xsq);
                xsq = fmaf(v[2*j+1], v[2*j+1], xsq);
                pk[j] = (__float_as_uint(v[2*j]) >> 16) |
                        (__float_as_uint(v[2*j+1]) & 0xffff0000u);
            }
            *(uint4*)(B + xwb) = make_uint4(pk[0], pk[1], pk[2], pk[3]);
        }
    };

    // ---- MFMA fragments: wave = M-half (wid>>2: 2 frags) x N-quarter
    // (wid&3: 4 frags) -> 8 MFMA per chunk per wave.
    const int l15 = lane & 15;
    const int lg  = lane >> 4;        // 8-ch k-slot
    int aoff[2], boff[4];
#pragma unroll
    for (int mf = 0; mf < 2; ++mf)
        aoff[mf] = XB + swz((wid >> 2) * 32 + mf * 16 + l15, lg);
#pragma unroll
    for (int nf = 0; nf < 4; ++nf)
        boff[nf] = swz((wid & 3) * 64 + nf * 16 + l15, lg);

    f32x4 acc[2][4];
#pragma unroll
    for (int mf = 0; mf < 2; ++mf)
#pragma unroll
        for (int nf = 0; nf < 4; ++nf)
            acc[mf][nf] = (f32x4){0.f, 0.f, 0.f, 0.f};

    auto compute = [&]() {
        short8 a[2], b[4];
#pragma unroll
        for (int mf = 0; mf < 2; ++mf) a[mf] = *(const short8*)(B + aoff[mf]);
#pragma unroll
        for (int nf = 0; nf < 4; ++nf) b[nf] = *(const short8*)(B + boff[nf]);
#pragma unroll
        for (int mf = 0; mf < 2; ++mf)
#pragma unroll
            for (int nf = 0; nf < 4; ++nf)
                acc[mf][nf] = __builtin_amdgcn_mfma_f32_16x16x32_bf16(
                    a[mf], b[nf], acc[mf][nf], 0, 0, 0);
    };

    // ---- K-loop: 8 chunks of 32 ch; {stage(c+1) | compute(c)} sync
    // {pack(c+1)} sync. F free at iteration start (packed last iteration).
    stage(0);
    __syncthreads();            // F(0) landed
    pack();
    __syncthreads();            // B(0) ready
    for (int c = 0; c < 8; ++c) {
        if (c < 7) stage(c + 1);     // DMA into F flies over MFMAs
        compute();                    // chunk c from B
        __syncthreads();              // F(c+1) landed; all waves done with B
        if (c < 7) pack();            // B <- chunk c+1
        __syncthreads();              // B ready
    }

    // ---- norms reduce; init tables (F dead now) ----
#pragma unroll
    for (int i = 0; i < 2; ++i) atomicAdd(&y2s[ypx[i]], ysq[i]);
    if (xw) atomicAdd(&x2s[xpx], xsq);
    for (int i = t; i < TBL; i += BLK) table[i] = 0xBF800000u;  // fmap(1.0f)
    __syncthreads();

    // ---- epilogue: d -> sigmoid -> label-masked min ----
    // C layout: col(n) = l&15, row(m) = (l>>4)*4 + reg.
#pragma unroll
    for (int mf = 0; mf < 2; ++mf) {
#pragma unroll
        for (int nf = 0; nf < 4; ++nf) {
#pragma unroll
            for (int r = 0; r < 4; ++r) {
                const int q = (wid >> 2) * 32 + mf * 16 + lg * 4 + r; // 0..63
                const int s = (wid & 3) * 64 + nf * 16 + l15;         // 0..255
                const int qr = q >> 3, qc = q & 7;
                const int sr = s >> 4, sc = s & 15;
                const int di = sr - qr, dj = sc - qc;
                const int lab = labs[s];
                if (di >= 0 && di <= 2 * MD && dj >= 0 && dj <= 2 * MD &&
                    lab >= 0 && lab < NC) {
                    const float d  = x2s[q] + y2s[s] - 2.0f * acc[mf][nf][r];
                    const float sg = 1.0f / (1.0f + __expf(-d));
                    atomicMin(&table[q * NC + lab], fmap(fmaf(2.0f, sg, -1.0f)));
                }
            }
        }
    }
    __syncthreads();

    // ---- write out[n][class][h0+qr][w0+qc] ----
    const size_t ob = (size_t)n * NC * HW;
    for (int i = t; i < TBL; i += BLK) {
        const int g = i >> 6;        // class
        const int q = i & 63;        // dest pixel
        const int qr = q >> 3, qc = q & 7;
        out[ob + (size_t)g * HW + (size_t)(h0 + qr) * Ww + (w0 + qc)] =
            funmap(table[q * NC + g]);
    }
}

extern "C" void kernel_launch(void* const* d_in, const int* in_sizes, int n_in,
                              void* d_out, int out_size, void* d_ws, size_t ws_size,
                              hipStream_t stream) {
    const float* x      = (const float*)d_in[0];
    const float* y      = (const float*)d_in[1];
    const int*   labels = (const int*)d_in[2];
    float*       out    = (float*)d_out;
    (void)in_sizes; (void)n_in; (void)out_size; (void)d_ws; (void)ws_size;

    propnet_fused<<<dim3(NBLK), dim3(BLK), 0, stream>>>(x, y, labels, out);
}